// Round 13
// baseline (66.232 us; speedup 1.0000x reference)
//
#include <hip/hip_runtime.h>
#include <cstdint>
#include <cstddef>

#define E_DIM 1024
#define PD 64            // proj dim
#define NP 128           // 2*proj dim
#define B_DIM 8
#define S_DIM 2048
#define M_TOT (B_DIM * S_DIM)   // 16384

#define BMR 32           // rows per block
#define BK 32
#define NCH (E_DIM / BK) // 32 chunks

typedef __attribute__((ext_vector_type(8))) short short8v;  // 8 bf16 (4 VGPR)
typedef __attribute__((ext_vector_type(4))) float f32x4;    // MFMA acc / vec IO

// two-fold truncation split: a = hi + lo at the fp32->bf16 boundary
__device__ __forceinline__ void cvt_hilo(const f32x4 v0, const f32x4 v1,
                                         short8v& h, short8v& l) {
    const unsigned MSK = 0xFFFF0000u;
    unsigned a0 = __float_as_uint(v0.x), a1 = __float_as_uint(v0.y);
    unsigned a2 = __float_as_uint(v0.z), a3 = __float_as_uint(v0.w);
    unsigned a4 = __float_as_uint(v1.x), a5 = __float_as_uint(v1.y);
    unsigned a6 = __float_as_uint(v1.z), a7 = __float_as_uint(v1.w);
    float l0 = v0.x - __uint_as_float(a0 & MSK);
    float l1 = v0.y - __uint_as_float(a1 & MSK);
    float l2 = v0.z - __uint_as_float(a2 & MSK);
    float l3 = v0.w - __uint_as_float(a3 & MSK);
    float l4 = v1.x - __uint_as_float(a4 & MSK);
    float l5 = v1.y - __uint_as_float(a5 & MSK);
    float l6 = v1.z - __uint_as_float(a6 & MSK);
    float l7 = v1.w - __uint_as_float(a7 & MSK);
    union { unsigned u[4]; short8v s; } H, L;
    H.u[0] = (a1 & MSK) | (a0 >> 16);
    H.u[1] = (a3 & MSK) | (a2 >> 16);
    H.u[2] = (a5 & MSK) | (a4 >> 16);
    H.u[3] = (a7 & MSK) | (a6 >> 16);
    L.u[0] = (__float_as_uint(l1) & MSK) | (__float_as_uint(l0) >> 16);
    L.u[1] = (__float_as_uint(l3) & MSK) | (__float_as_uint(l2) >> 16);
    L.u[2] = (__float_as_uint(l5) & MSK) | (__float_as_uint(l4) >> 16);
    L.u[3] = (__float_as_uint(l7) & MSK) | (__float_as_uint(l6) >> 16);
    h = H.s; l = L.s;
}

// ---------------- K0: pre-convert W -> bf16 hi/lo images in staged layout ----------------
// img[ch][kq][col][8] bf16.
__global__ __launch_bounds__(256) void conv_w(const float* __restrict__ W,
                                              ushort* __restrict__ hiImg,
                                              ushort* __restrict__ loImg) {
    const int t = blockIdx.x * 256 + threadIdx.x;  // 16384 threads
    const int c  = t & 127;
    const int q  = (t >> 7) & 3;
    const int ch = t >> 9;
    const float* src = W + (size_t)c * E_DIM + ch * 32 + q * 8;
    const f32x4 v0 = *(const f32x4*)src;
    const f32x4 v1 = *(const f32x4*)(src + 4);
    short8v h, l;
    cvt_hilo(v0, v1, h, l);
    const size_t off = ((size_t)(ch * 4 + q) * NP + c) * 8;
    *(short8v*)&hiImg[off] = h;
    *(short8v*)&loImg[off] = l;
}

// ---------------- K1: single-pass bf16-MFMA GEMM, fully reg-staged pipeline ----------------
// qk[m][p] = sum_k A[m][k]*W[p][k] + bias[p].  W frags: global(L2)->VGPR, prefetch
// depth 2 (no LDS). A: global->VGPR (depth 2) -> ds_write_b128 swizzled (depth 1)
// -> ds_read_b128 frags. All VMEM waits are compiler-precise counted; raw s_barrier,
// one per chunk, no vmcnt drains anywhere in the loop.
__global__ __launch_bounds__(256, 2) void gemm_qk(const float* __restrict__ A,
                                                  const ushort* __restrict__ hiImg,
                                                  const ushort* __restrict__ loImg,
                                                  const float* __restrict__ bias,
                                                  float* __restrict__ qk) {
    __shared__ __align__(16) float As[2][BMR][BK];   // 8 KB total
    const int tid = threadIdx.x;
    const int m0  = blockIdx.x * BMR;
    const int w   = tid >> 6;       // wave id
    const int ln  = tid & 63;
    const int lr  = ln >> 3;        // staging row in 8-row group (0..7)
    const int g8  = ln & 7;         // staging k-granule (linear in global)
    const int row16 = ln & 15;      // frag row/col
    const int kq    = ln >> 4;      // k-quadrant
    const int r7    = row16 & 7;
    const int sg0 = ((((kq << 1) | 0) ^ r7) & 7) << 2;  // A slot offsets (floats)
    const int sg1 = ((((kq << 1) | 1) ^ r7) & 7) << 2;

    // A global source: linear granule (coalesced 128B per 8-lane row group)
    const float* aS = A + (size_t)(m0 + w * 8 + lr) * E_DIM + (g8 << 2);
    // A LDS write slot: slot s of row r holds global granule s ^ (r&7); here key = lr
    float* const aDst0 = &As[0][0][0] + (w * 8 + lr) * BK + ((g8 ^ lr) << 2);
    float* const aDst1 = &As[1][0][0] + (w * 8 + lr) * BK + ((g8 ^ lr) << 2);
    // W image per-lane base: frag (fj) at + fj*128; per-chunk stride 4096 ushorts
    const ushort* hS = hiImg + ((size_t)kq * NP + w * 32 + row16) * 8;
    const ushort* lS = loImg + ((size_t)kq * NP + w * 32 + row16) * 8;

    float bias2[2];
    bias2[0] = bias[w * 32 + row16];
    bias2[1] = bias[w * 32 + 16 + row16];

    f32x4 acc[2][2];
#pragma unroll
    for (int i = 0; i < 2; ++i)
#pragma unroll
        for (int j = 0; j < 2; ++j) acc[i][j] = (f32x4){0.f, 0.f, 0.f, 0.f};

    // prefetch registers: chunk c lives in slot [c&1]
    f32x4 aP0, aP1;
    short8v wh00, wh01, wl00, wl01;   // parity 0
    short8v wh10, wh11, wl10, wl11;   // parity 1

    // prologue: load chunks 0,1; write chunk 0 to LDS
    aP0 = *(const f32x4*)(aS);
    aP1 = *(const f32x4*)(aS + BK);
    wh00 = *(const short8v*)(hS);
    wh01 = *(const short8v*)(hS + 128);
    wl00 = *(const short8v*)(lS);
    wl01 = *(const short8v*)(lS + 128);
    wh10 = *(const short8v*)(hS + 4096);
    wh11 = *(const short8v*)(hS + 4096 + 128);
    wl10 = *(const short8v*)(lS + 4096);
    wl11 = *(const short8v*)(lS + 4096 + 128);
    *(f32x4*)aDst0 = aP0;
    asm volatile("s_waitcnt lgkmcnt(0)" ::: "memory");
    __builtin_amdgcn_sched_barrier(0);

#define GBODY(P, CH, APcur, APother, WH0, WH1, WL0, WL1, DSTother, SRCbuf)          \
    {                                                                               \
        __builtin_amdgcn_s_barrier();                                               \
        __builtin_amdgcn_sched_barrier(0);                                          \
        if ((CH) + 1 < NCH) { *(f32x4*)(DSTother) = APother; }                      \
        if ((CH) + 2 < NCH) {                                                       \
            APcur = *(const f32x4*)(aS + ((CH) + 2) * BK);                          \
        }                                                                           \
        short8v ah0, al0, ah1, al1;                                                 \
        {                                                                           \
            const float* b0 = &As[SRCbuf][row16][0];                                \
            cvt_hilo(*(const f32x4*)(b0 + sg0), *(const f32x4*)(b0 + sg1), ah0, al0); \
            const float* b1 = &As[SRCbuf][16 + row16][0];                           \
            cvt_hilo(*(const f32x4*)(b1 + sg0), *(const f32x4*)(b1 + sg1), ah1, al1); \
        }                                                                           \
        acc[0][0] = __builtin_amdgcn_mfma_f32_16x16x32_bf16(ah0, WH0, acc[0][0], 0, 0, 0); \
        acc[0][0] = __builtin_amdgcn_mfma_f32_16x16x32_bf16(ah0, WL0, acc[0][0], 0, 0, 0); \
        acc[0][0] = __builtin_amdgcn_mfma_f32_16x16x32_bf16(al0, WH0, acc[0][0], 0, 0, 0); \
        acc[0][1] = __builtin_amdgcn_mfma_f32_16x16x32_bf16(ah0, WH1, acc[0][1], 0, 0, 0); \
        acc[0][1] = __builtin_amdgcn_mfma_f32_16x16x32_bf16(ah0, WL1, acc[0][1], 0, 0, 0); \
        acc[0][1] = __builtin_amdgcn_mfma_f32_16x16x32_bf16(al0, WH1, acc[0][1], 0, 0, 0); \
        acc[1][0] = __builtin_amdgcn_mfma_f32_16x16x32_bf16(ah1, WH0, acc[1][0], 0, 0, 0); \
        acc[1][0] = __builtin_amdgcn_mfma_f32_16x16x32_bf16(ah1, WL0, acc[1][0], 0, 0, 0); \
        acc[1][0] = __builtin_amdgcn_mfma_f32_16x16x32_bf16(al1, WH0, acc[1][0], 0, 0, 0); \
        acc[1][1] = __builtin_amdgcn_mfma_f32_16x16x32_bf16(ah1, WH1, acc[1][1], 0, 0, 0); \
        acc[1][1] = __builtin_amdgcn_mfma_f32_16x16x32_bf16(ah1, WL1, acc[1][1], 0, 0, 0); \
        acc[1][1] = __builtin_amdgcn_mfma_f32_16x16x32_bf16(al1, WH1, acc[1][1], 0, 0, 0); \
        if ((CH) + 2 < NCH) {                                                       \
            WH0 = *(const short8v*)(hS + (size_t)((CH) + 2) * 4096);                \
            WH1 = *(const short8v*)(hS + (size_t)((CH) + 2) * 4096 + 128);          \
            WL0 = *(const short8v*)(lS + (size_t)((CH) + 2) * 4096);                \
            WL1 = *(const short8v*)(lS + (size_t)((CH) + 2) * 4096 + 128);          \
        }                                                                           \
        asm volatile("s_waitcnt lgkmcnt(0)" ::: "memory");                          \
        __builtin_amdgcn_sched_barrier(0);                                          \
    }

#pragma unroll 1
    for (int c2 = 0; c2 < NCH / 2; ++c2) {
        const int ch0 = 2 * c2;
        // parity 0: reads As[0], writes chunk ch0+1 into As[1]
        GBODY(0, ch0, aP0, aP1, wh00, wh01, wl00, wl01, aDst1, 0)
        const int ch1 = 2 * c2 + 1;
        // parity 1: reads As[1], writes chunk ch1+1 into As[0]
        GBODY(1, ch1, aP1, aP0, wh10, wh11, wl10, wl11, aDst0, 1)
    }
#undef GBODY

    // C/D layout (m89): col = lane&15, row = (lane>>4)*4 + r
#pragma unroll
    for (int fi = 0; fi < 2; ++fi)
#pragma unroll
        for (int fj = 0; fj < 2; ++fj) {
#pragma unroll
            for (int r = 0; r < 4; ++r) {
                const int m = m0 + fi * 16 + kq * 4 + r;
                const int p = w * 32 + fj * 16 + row16;
                qk[(size_t)m * NP + p] = acc[fi][fj][r] + bias2[fj];
            }
        }
}

// ---------------- K2: neighbor scores + 2-way softmax (bias already in qk) ----------------
__global__ __launch_bounds__(256) void neighbor_probs(const float* __restrict__ qk,
                                                      float* __restrict__ p0,
                                                      float* __restrict__ p1) {
    const int m = blockIdx.x * 4 + (threadIdx.x >> 6);  // position index m = s*B+b
    const int lane = threadIdx.x & 63;
    const int s = m >> 3;   // / B_DIM
    const int b = m & 7;    // % B_DIM

    const float q = qk[(size_t)m * NP + lane];
    const float kn = (s < S_DIM - 1) ? qk[(size_t)(m + B_DIM) * NP + PD + lane] : 0.f;
    const float kp = (s > 0) ? qk[(size_t)(m - B_DIM) * NP + PD + lane] : 0.f;
    float f = q * kn;   // fwd partial: query[s] . key[s+1]
    float g = q * kp;   // bwd partial: query[s] . key[s-1]
#pragma unroll
    for (int off = 32; off; off >>= 1) {
        f += __shfl_xor(f, off);
        g += __shfl_xor(g, off);
    }
    if (lane == 0) {
        const float s0 = f * (1.f / (float)E_DIM);
        const float s1 = g * (1.f / (float)E_DIM);
        float P0, P1;
        if (s == S_DIM - 1) { P0 = 0.f; P1 = 1.f; }
        else if (s == 0)    { P0 = 1.f; P1 = 0.f; }
        else {
            const float mx = fmaxf(s0, s1);
            const float e0 = __expf(s0 - mx), e1 = __expf(s1 - mx);
            const float inv = 1.f / (e0 + e1);
            P0 = e0 * inv; P1 = e1 * inv;
        }
        p0[b * S_DIM + s] = P0;
        p1[b * S_DIM + s] = P1;
    }
}

// ---------------- K3: combine (flat roll), neighbor_attn out, log, exclusive scan ----------------
__global__ __launch_bounds__(256) void combine_scan(const float* __restrict__ p0,
                                                    const float* __restrict__ p1,
                                                    const float* __restrict__ prior,
                                                    float* __restrict__ out_na,
                                                    float* __restrict__ cs) {
    const int b = blockIdx.x;
    const int tid = threadIdx.x;
    __shared__ float sh[256];

    const int base = b * S_DIM + tid * 8;
    float incl[8];
    float run = 0.f;
#pragma unroll
    for (int u = 0; u < 8; ++u) {
        const int fidx = base + u;
        int nf = fidx + 1;
        if (nf == B_DIM * S_DIM) nf = 0;   // torch .roll on flattened tensor wraps globally
        const float P0 = p0[fidx];
        const float sp = p1[nf];
        const float pr = prior[fidx];
        const float na = pr + (1.f - pr) * sqrtf(P0 * sp + 1e-6f);
        out_na[fidx] = na;
        run += __logf(na);
        incl[u] = run;
    }
    sh[tid] = run;
    __syncthreads();
    for (int off = 1; off < 256; off <<= 1) {
        float v = sh[tid];
        if (tid >= off) v += sh[tid - off];
        __syncthreads();
        sh[tid] = v;
        __syncthreads();
    }
    const float offset = (tid > 0) ? sh[tid - 1] : 0.f;
#pragma unroll
    for (int u = 0; u < 8; ++u) {
        cs[base + u] = offset + ((u > 0) ? incl[u - 1] : 0.f);  // exclusive prefix
    }
}

// ---------------- K4: big output C[b,i,j] = exp(sign*(cs[j]-cs[i])), 0 on diag ----------------
__global__ __launch_bounds__(256) void big_out(const float* __restrict__ cs,
                                               float* __restrict__ out) {
    const int bi = blockIdx.x;          // b*S + i
    const int b = bi >> 11;             // / S_DIM
    const int i = bi & (S_DIM - 1);
    const float ci = cs[b * S_DIM + i];
    const float* crow = cs + (size_t)b * S_DIM;
    float* orow = out + (size_t)bi * S_DIM;
    const int j0 = threadIdx.x * 8;
#pragma unroll
    for (int h = 0; h < 2; ++h) {
        const int j = j0 + h * 4;
        const f32x4 cj = *(const f32x4*)&crow[j];
        f32x4 o;
        {
            const int jj = j + 0; const float m = (jj > i) ? (cj.x - ci) : (ci - cj.x);
            o.x = (jj == i) ? 0.f : __expf(m);
        }
        {
            const int jj = j + 1; const float m = (jj > i) ? (cj.y - ci) : (ci - cj.y);
            o.y = (jj == i) ? 0.f : __expf(m);
        }
        {
            const int jj = j + 2; const float m = (jj > i) ? (cj.z - ci) : (ci - cj.z);
            o.z = (jj == i) ? 0.f : __expf(m);
        }
        {
            const int jj = j + 3; const float m = (jj > i) ? (cj.w - ci) : (ci - cj.w);
            o.w = (jj == i) ? 0.f : __expf(m);
        }
        *(f32x4*)&orow[j] = o;   // regular store (NT store was the r10 regression)
    }
}

extern "C" void kernel_launch(void* const* d_in, const int* in_sizes, int n_in,
                              void* d_out, int out_size, void* d_ws, size_t ws_size,
                              hipStream_t stream) {
    const float* context = (const float*)d_in[0];   // (S,B,E) fp32
    const float* prior   = (const float*)d_in[1];   // (B,S) fp32
    const float* W       = (const float*)d_in[2];   // (128,1024) fp32
    const float* bias    = (const float*)d_in[3];   // (128,) fp32
    float* out = (float*)d_out;

    float* qk = (float*)d_ws;                          // 16384*128 floats (8 MB)
    float* p0 = qk + (size_t)M_TOT * NP;               // 16384 floats
    float* p1 = p0 + M_TOT;                            // 16384 floats
    float* cs = p1 + M_TOT;                            // 16384 floats
    // W bf16 hi/lo images (256 KB each) live in d_out's C-region; conv_w writes,
    // gemm reads, big_out overwrites afterwards (stream-ordered, safe)
    ushort* hiImg = (ushort*)out;                      // 128K ushorts
    ushort* loImg = hiImg + (size_t)NP * E_DIM;        // 128K ushorts
    float* na_out = out + (size_t)B_DIM * S_DIM * S_DIM;  // second output

    conv_w<<<64, 256, 0, stream>>>(W, hiImg, loImg);
    gemm_qk<<<M_TOT / BMR, 256, 0, stream>>>(context, hiImg, loImg, bias, qk);
    neighbor_probs<<<M_TOT / 4, 256, 0, stream>>>(qk, p0, p1);
    combine_scan<<<B_DIM, 256, 0, stream>>>(p0, p1, prior, na_out, cs);
    big_out<<<M_TOT, 256, 0, stream>>>(cs, out);
}

// Round 14
// 64.043 us; speedup vs baseline: 1.0342x; 1.0342x over previous
//
#include <hip/hip_runtime.h>
#include <cstdint>
#include <cstddef>

#define E_DIM 1024
#define PD 64            // proj dim
#define NP 128           // 2*proj dim
#define B_DIM 8
#define S_DIM 2048
#define M_TOT (B_DIM * S_DIM)   // 16384

#define BMR 32           // rows per block
#define BK 32
#define NCHH 16          // chunks per K-half (in-block split-K)

typedef __attribute__((ext_vector_type(8))) short short8v;  // 8 bf16 (4 VGPR)
typedef __attribute__((ext_vector_type(4))) float f32x4;    // MFMA acc / vec IO

__device__ __forceinline__ void gload16(const void* g, void* l) {
    __builtin_amdgcn_global_load_lds(
        (const __attribute__((address_space(1))) unsigned int*)g,
        (__attribute__((address_space(3))) unsigned int*)(uintptr_t)l,
        16, 0, 0);
}

// two-fold truncation split: a = hi + lo at the fp32->bf16 boundary
__device__ __forceinline__ void cvt_hilo(const f32x4 v0, const f32x4 v1,
                                         short8v& h, short8v& l) {
    const unsigned MSK = 0xFFFF0000u;
    unsigned a0 = __float_as_uint(v0.x), a1 = __float_as_uint(v0.y);
    unsigned a2 = __float_as_uint(v0.z), a3 = __float_as_uint(v0.w);
    unsigned a4 = __float_as_uint(v1.x), a5 = __float_as_uint(v1.y);
    unsigned a6 = __float_as_uint(v1.z), a7 = __float_as_uint(v1.w);
    float l0 = v0.x - __uint_as_float(a0 & MSK);
    float l1 = v0.y - __uint_as_float(a1 & MSK);
    float l2 = v0.z - __uint_as_float(a2 & MSK);
    float l3 = v0.w - __uint_as_float(a3 & MSK);
    float l4 = v1.x - __uint_as_float(a4 & MSK);
    float l5 = v1.y - __uint_as_float(a5 & MSK);
    float l6 = v1.z - __uint_as_float(a6 & MSK);
    float l7 = v1.w - __uint_as_float(a7 & MSK);
    union { unsigned u[4]; short8v s; } H, L;
    H.u[0] = (a1 & MSK) | (a0 >> 16);
    H.u[1] = (a3 & MSK) | (a2 >> 16);
    H.u[2] = (a5 & MSK) | (a4 >> 16);
    H.u[3] = (a7 & MSK) | (a6 >> 16);
    L.u[0] = (__float_as_uint(l1) & MSK) | (__float_as_uint(l0) >> 16);
    L.u[1] = (__float_as_uint(l3) & MSK) | (__float_as_uint(l2) >> 16);
    L.u[2] = (__float_as_uint(l5) & MSK) | (__float_as_uint(l4) >> 16);
    L.u[3] = (__float_as_uint(l7) & MSK) | (__float_as_uint(l6) >> 16);
    h = H.s; l = L.s;
}

// ---------------- K0: pre-convert W -> bf16 hi/lo images in staged layout ----------------
// img[ch][kq][col][8] bf16 (ch = global 32-wide K chunk, kq = k-quadrant).
__global__ __launch_bounds__(256) void conv_w(const float* __restrict__ W,
                                              ushort* __restrict__ hiImg,
                                              ushort* __restrict__ loImg) {
    const int t = blockIdx.x * 256 + threadIdx.x;  // 16384 threads
    const int c  = t & 127;
    const int q  = (t >> 7) & 3;
    const int ch = t >> 9;
    const float* src = W + (size_t)c * E_DIM + ch * 32 + q * 8;
    const f32x4 v0 = *(const f32x4*)src;
    const f32x4 v1 = *(const f32x4*)(src + 4);
    short8v h, l;
    cvt_hilo(v0, v1, h, l);
    const size_t off = ((size_t)(ch * 4 + q) * NP + c) * 8;
    *(short8v*)&hiImg[off] = h;
    *(short8v*)&loImg[off] = l;
}

// ---------------- K1: bf16-MFMA GEMM, 8 waves, in-block split-K ----------------
// qk[m][p] = sum_k A[m][k]*W[p][k] + bias[p].  Waves 0-3: K-half 0; waves 4-7:
// K-half 1. Each wave: 32 rows x 32 cols, 16 serial chunks. 4 waves/SIMD
// (launch_bounds(512,4)) so barrier/drain stalls are covered by TLP.
// A: gload16 into linear LDS with XOR-preswizzled source (r11 pattern, 1 per
// wave per chunk). W: bf16 hi/lo image frags global(L2)->VGPR, parity prefetch.
// Epilogue: half-1 acc -> LDS, half-0 adds + bias -> qk.
__global__ __launch_bounds__(512, 4) void gemm_qk(const float* __restrict__ A,
                                                  const ushort* __restrict__ hiImg,
                                                  const ushort* __restrict__ loImg,
                                                  const float* __restrict__ bias,
                                                  float* __restrict__ qk) {
    __shared__ __align__(16) float As[2][2][BMR][BK];  // [half][buf][row][k] 16 KB
    __shared__ __align__(16) float Cred[BMR][NP];      // 16 KB
    const int tid = threadIdx.x;
    const int m0  = blockIdx.x * BMR;
    const int w   = tid >> 6;       // wave 0..7
    const int h   = w >> 2;         // K-half
    const int wv  = w & 3;          // wave within half -> col group wv*32
    const int ln  = tid & 63;
    const int lr  = ln >> 3;
    const int g8  = ln & 7;
    const int row16 = ln & 15;
    const int kq    = ln >> 4;
    const int r7    = row16 & 7;
    const int sg0 = ((((kq << 1) | 0) ^ r7) & 7) << 2;
    const int sg1 = ((((kq << 1) | 1) ^ r7) & 7) << 2;

    const int srow = wv * 8 + lr;   // staging row 0..31 (4 waves cover 32 rows)
    const float* aS = A + (size_t)(m0 + srow) * E_DIM + h * (NCHH * BK)
                        + ((g8 ^ (srow & 7)) << 2);
    // W image per-lane base for this half; frag fj at +fj*128; chunk stride 4096
    const ushort* hS = hiImg + (size_t)(h * NCHH) * 4096
                             + ((size_t)kq * NP + wv * 32 + row16) * 8;
    const ushort* lS = loImg + (size_t)(h * NCHH) * 4096
                             + ((size_t)kq * NP + wv * 32 + row16) * 8;

    float bias2[2];
    bias2[0] = bias[wv * 32 + row16];
    bias2[1] = bias[wv * 32 + 16 + row16];

    f32x4 acc[2][2];
#pragma unroll
    for (int i = 0; i < 2; ++i)
#pragma unroll
        for (int j = 0; j < 2; ++j) acc[i][j] = (f32x4){0.f, 0.f, 0.f, 0.f};

    // W parity prefetch registers
    short8v whA0, whA1, wlA0, wlA1;   // parity 0
    short8v whB0, whB1, wlB0, wlB1;   // parity 1

    // prologue: stage A chunk 0 (buf 0), load W chunk 0 (parity 0)
    gload16(aS, &As[h][0][wv * 8][0]);
    whA0 = *(const short8v*)(hS);
    whA1 = *(const short8v*)(hS + 128);
    wlA0 = *(const short8v*)(lS);
    wlA1 = *(const short8v*)(lS + 128);

#define GBODY(CH, WH0, WH1, WL0, WL1, NWH0, NWH1, NWL0, NWL1)                       \
    {                                                                               \
        const int buf = (CH) & 1;                                                   \
        __syncthreads();  /* drains gload16 + syncs both halves */                  \
        if ((CH) + 1 < NCHH) {                                                      \
            gload16(aS + ((CH) + 1) * BK, &As[h][buf ^ 1][wv * 8][0]);              \
            NWH0 = *(const short8v*)(hS + (size_t)((CH) + 1) * 4096);               \
            NWH1 = *(const short8v*)(hS + (size_t)((CH) + 1) * 4096 + 128);         \
            NWL0 = *(const short8v*)(lS + (size_t)((CH) + 1) * 4096);               \
            NWL1 = *(const short8v*)(lS + (size_t)((CH) + 1) * 4096 + 128);         \
        }                                                                           \
        short8v ah0, al0, ah1, al1;                                                 \
        {                                                                           \
            const float* b0 = &As[h][buf][row16][0];                                \
            cvt_hilo(*(const f32x4*)(b0 + sg0), *(const f32x4*)(b0 + sg1), ah0, al0); \
            const float* b1 = &As[h][buf][16 + row16][0];                           \
            cvt_hilo(*(const f32x4*)(b1 + sg0), *(const f32x4*)(b1 + sg1), ah1, al1); \
        }                                                                           \
        acc[0][0] = __builtin_amdgcn_mfma_f32_16x16x32_bf16(ah0, WH0, acc[0][0], 0, 0, 0); \
        acc[0][0] = __builtin_amdgcn_mfma_f32_16x16x32_bf16(ah0, WL0, acc[0][0], 0, 0, 0); \
        acc[0][0] = __builtin_amdgcn_mfma_f32_16x16x32_bf16(al0, WH0, acc[0][0], 0, 0, 0); \
        acc[0][1] = __builtin_amdgcn_mfma_f32_16x16x32_bf16(ah0, WH1, acc[0][1], 0, 0, 0); \
        acc[0][1] = __builtin_amdgcn_mfma_f32_16x16x32_bf16(ah0, WL1, acc[0][1], 0, 0, 0); \
        acc[0][1] = __builtin_amdgcn_mfma_f32_16x16x32_bf16(al0, WH1, acc[0][1], 0, 0, 0); \
        acc[1][0] = __builtin_amdgcn_mfma_f32_16x16x32_bf16(ah1, WH0, acc[1][0], 0, 0, 0); \
        acc[1][0] = __builtin_amdgcn_mfma_f32_16x16x32_bf16(ah1, WL0, acc[1][0], 0, 0, 0); \
        acc[1][0] = __builtin_amdgcn_mfma_f32_16x16x32_bf16(al1, WH0, acc[1][0], 0, 0, 0); \
        acc[1][1] = __builtin_amdgcn_mfma_f32_16x16x32_bf16(ah1, WH1, acc[1][1], 0, 0, 0); \
        acc[1][1] = __builtin_amdgcn_mfma_f32_16x16x32_bf16(ah1, WL1, acc[1][1], 0, 0, 0); \
        acc[1][1] = __builtin_amdgcn_mfma_f32_16x16x32_bf16(al1, WH1, acc[1][1], 0, 0, 0); \
    }

#pragma unroll 1
    for (int c2 = 0; c2 < NCHH / 2; ++c2) {
        GBODY(2 * c2,     whA0, whA1, wlA0, wlA1, whB0, whB1, wlB0, wlB1)
        GBODY(2 * c2 + 1, whB0, whB1, wlB0, wlB1, whA0, whA1, wlA0, wlA1)
    }
#undef GBODY

    // combine halves: half 1 dumps acc to LDS; half 0 adds + bias and stores.
    // C/D layout (m89): col = lane&15, row = (lane>>4)*4 + r
    if (h == 1) {
#pragma unroll
        for (int fi = 0; fi < 2; ++fi)
#pragma unroll
            for (int fj = 0; fj < 2; ++fj)
#pragma unroll
                for (int r = 0; r < 4; ++r)
                    Cred[fi * 16 + kq * 4 + r][wv * 32 + fj * 16 + row16] = acc[fi][fj][r];
    }
    __syncthreads();
    if (h == 0) {
#pragma unroll
        for (int fi = 0; fi < 2; ++fi)
#pragma unroll
            for (int fj = 0; fj < 2; ++fj) {
#pragma unroll
                for (int r = 0; r < 4; ++r) {
                    const int mr = fi * 16 + kq * 4 + r;
                    const int p  = wv * 32 + fj * 16 + row16;
                    qk[(size_t)(m0 + mr) * NP + p] =
                        acc[fi][fj][r] + Cred[mr][p] + bias2[fj];
                }
            }
    }
}

// ---------------- K2: neighbor scores + 2-way softmax (bias already in qk) ----------------
__global__ __launch_bounds__(256) void neighbor_probs(const float* __restrict__ qk,
                                                      float* __restrict__ p0,
                                                      float* __restrict__ p1) {
    const int m = blockIdx.x * 4 + (threadIdx.x >> 6);  // position index m = s*B+b
    const int lane = threadIdx.x & 63;
    const int s = m >> 3;   // / B_DIM
    const int b = m & 7;    // % B_DIM

    const float q = qk[(size_t)m * NP + lane];
    const float kn = (s < S_DIM - 1) ? qk[(size_t)(m + B_DIM) * NP + PD + lane] : 0.f;
    const float kp = (s > 0) ? qk[(size_t)(m - B_DIM) * NP + PD + lane] : 0.f;
    float f = q * kn;   // fwd partial: query[s] . key[s+1]
    float g = q * kp;   // bwd partial: query[s] . key[s-1]
#pragma unroll
    for (int off = 32; off; off >>= 1) {
        f += __shfl_xor(f, off);
        g += __shfl_xor(g, off);
    }
    if (lane == 0) {
        const float s0 = f * (1.f / (float)E_DIM);
        const float s1 = g * (1.f / (float)E_DIM);
        float P0, P1;
        if (s == S_DIM - 1) { P0 = 0.f; P1 = 1.f; }
        else if (s == 0)    { P0 = 1.f; P1 = 0.f; }
        else {
            const float mx = fmaxf(s0, s1);
            const float e0 = __expf(s0 - mx), e1 = __expf(s1 - mx);
            const float inv = 1.f / (e0 + e1);
            P0 = e0 * inv; P1 = e1 * inv;
        }
        p0[b * S_DIM + s] = P0;
        p1[b * S_DIM + s] = P1;
    }
}

// ---------------- K3: combine (flat roll), neighbor_attn out, log, exclusive scan ----------------
__global__ __launch_bounds__(256) void combine_scan(const float* __restrict__ p0,
                                                    const float* __restrict__ p1,
                                                    const float* __restrict__ prior,
                                                    float* __restrict__ out_na,
                                                    float* __restrict__ cs) {
    const int b = blockIdx.x;
    const int tid = threadIdx.x;
    __shared__ float sh[256];

    const int base = b * S_DIM + tid * 8;
    float incl[8];
    float run = 0.f;
#pragma unroll
    for (int u = 0; u < 8; ++u) {
        const int fidx = base + u;
        int nf = fidx + 1;
        if (nf == B_DIM * S_DIM) nf = 0;   // torch .roll on flattened tensor wraps globally
        const float P0 = p0[fidx];
        const float sp = p1[nf];
        const float pr = prior[fidx];
        const float na = pr + (1.f - pr) * sqrtf(P0 * sp + 1e-6f);
        out_na[fidx] = na;
        run += __logf(na);
        incl[u] = run;
    }
    sh[tid] = run;
    __syncthreads();
    for (int off = 1; off < 256; off <<= 1) {
        float v = sh[tid];
        if (tid >= off) v += sh[tid - off];
        __syncthreads();
        sh[tid] = v;
        __syncthreads();
    }
    const float offset = (tid > 0) ? sh[tid - 1] : 0.f;
#pragma unroll
    for (int u = 0; u < 8; ++u) {
        cs[base + u] = offset + ((u > 0) ? incl[u - 1] : 0.f);  // exclusive prefix
    }
}

// ---------------- K4: big output C[b,i,j] = exp(sign*(cs[j]-cs[i])), 0 on diag ----------------
__global__ __launch_bounds__(256) void big_out(const float* __restrict__ cs,
                                               float* __restrict__ out) {
    const int bi = blockIdx.x;          // b*S + i
    const int b = bi >> 11;             // / S_DIM
    const int i = bi & (S_DIM - 1);
    const float ci = cs[b * S_DIM + i];
    const float* crow = cs + (size_t)b * S_DIM;
    float* orow = out + (size_t)bi * S_DIM;
    const int j0 = threadIdx.x * 8;
#pragma unroll
    for (int h = 0; h < 2; ++h) {
        const int j = j0 + h * 4;
        const f32x4 cj = *(const f32x4*)&crow[j];
        f32x4 o;
        {
            const int jj = j + 0; const float m = (jj > i) ? (cj.x - ci) : (ci - cj.x);
            o.x = (jj == i) ? 0.f : __expf(m);
        }
        {
            const int jj = j + 1; const float m = (jj > i) ? (cj.y - ci) : (ci - cj.y);
            o.y = (jj == i) ? 0.f : __expf(m);
        }
        {
            const int jj = j + 2; const float m = (jj > i) ? (cj.z - ci) : (ci - cj.z);
            o.z = (jj == i) ? 0.f : __expf(m);
        }
        {
            const int jj = j + 3; const float m = (jj > i) ? (cj.w - ci) : (ci - cj.w);
            o.w = (jj == i) ? 0.f : __expf(m);
        }
        *(f32x4*)&orow[j] = o;   // regular store (NT store was the r10 regression)
    }
}

extern "C" void kernel_launch(void* const* d_in, const int* in_sizes, int n_in,
                              void* d_out, int out_size, void* d_ws, size_t ws_size,
                              hipStream_t stream) {
    const float* context = (const float*)d_in[0];   // (S,B,E) fp32
    const float* prior   = (const float*)d_in[1];   // (B,S) fp32
    const float* W       = (const float*)d_in[2];   // (128,1024) fp32
    const float* bias    = (const float*)d_in[3];   // (128,) fp32
    float* out = (float*)d_out;

    float* qk = (float*)d_ws;                          // 16384*128 floats (8 MB)
    float* p0 = qk + (size_t)M_TOT * NP;               // 16384 floats
    float* p1 = p0 + M_TOT;                            // 16384 floats
    float* cs = p1 + M_TOT;                            // 16384 floats
    // W bf16 hi/lo images (256 KB each) live in d_out's C-region; conv_w writes,
    // gemm reads, big_out overwrites afterwards (stream-ordered, safe)
    ushort* hiImg = (ushort*)out;                      // 128K ushorts
    ushort* loImg = hiImg + (size_t)NP * E_DIM;        // 128K ushorts
    float* na_out = out + (size_t)B_DIM * S_DIM * S_DIM;  // second output

    conv_w<<<64, 256, 0, stream>>>(W, hiImg, loImg);
    gemm_qk<<<M_TOT / BMR, 512, 0, stream>>>(context, hiImg, loImg, bias, qk);
    neighbor_probs<<<M_TOT / 4, 256, 0, stream>>>(qk, p0, p1);
    combine_scan<<<B_DIM, 256, 0, stream>>>(p0, p1, prior, na_out, cs);
    big_out<<<M_TOT, 256, 0, stream>>>(cs, out);
}